// Round 6
// baseline (316.935 us; speedup 1.0000x reference)
//
#include <hip/hip_runtime.h>
#include <hip/hip_fp16.h>

// Problem constants (fixed by the reference setup)
#define N_NODES 50000
#define IN_DIM 256
#define OUT_DIM 128
#define NNZ 800000          // nnz for feat, adj1, adj2 each
#define SCAN_N (3 * N_NODES)        // 150000 row counters (feat | adj1 | adj2)
#define TOTAL_NNZ (3 * NNZ)         // 2.4M sorted entries
#define SCAN_BLOCKS ((SCAN_N + 255) / 256)   // 586
#define NPART 8                      // one row-partition per XCD
#define PART_W (N_NODES / NPART)     // 6250 rows per partition

// Level-1 per-partition bucket capacity.
// Expected 2.4M/8 = 300000, sigma ~512; 310016 = +19.6 sigma, multiple of 256.
#define BCAP 310016

// Level-2 sub-buckets: 64 per partition, 98 rows each (64*98=6272 >= 6250).
// Expected entries 2.4M*98/50000 = 4704, sigma ~68; 6144 = +21 sigma = 12*512.
#define NSUB 64
#define SUBW 98
#define SUBCAP 6144
#define ENT_B 4096                   // entries per subbucket_kernel block (256 thr x 16)
#define BBLK_B ((BCAP + ENT_B - 1) / ENT_B)   // 76 blocks per partition

// adj_gather dim-slicing: 8 slices of 16 output dims; slice s pinned to XCD s
// via blockIdx&7. Per-XCD working set = 2 tables x 50000 x 32 B = 3.2 MB < 4 MB L2.
#define NSLICE 8
#define ADJ_RC ((N_NODES + 63) / 64)  // 782 row-chunks of 64 rows

// Native clang vector types — __builtin_nontemporal_* requires these.
typedef float vf4 __attribute__((ext_vector_type(4)));

// Packed entry: [col:16 | fp16(val):16].  adj cols < 50000 < 65536, feat cols < 256.
static __device__ __forceinline__ unsigned pack_cv(int c, float v) {
    return ((unsigned)c << 16) | (unsigned)__half_as_ushort(__float2half(v));
}
static __device__ __forceinline__ int   upk_c(unsigned pk) { return (int)(pk >> 16); }
static __device__ __forceinline__ float upk_v(unsigned pk) {
    return __half2float(__ushort_as_half((unsigned short)(pk & 0xffffu)));
}
static __device__ __forceinline__ float h2f(unsigned short h) {
    return __half2float(__ushort_as_half(h));
}

// -----------------------------------------------------------------------------
// CSR build, three-level counting sort (KNOWN-GOOD round-2 pipeline):
//   A (bucket_kernel):    read every edge once, LDS-group by partition (row/6250),
//                         append chunks (~96 entries) to per-partition buckets.
//   B (subbucket_kernel): partition bucket -> 64 sub-buckets (98-row ranges).
//   C1 (subhist_kernel):  per-sub-bucket LDS histogram -> cnt (plain stores).
//   scan:                 global exclusive scan over 150K counters -> starts.
//   C2 (sort_write_kernel): per-sub-bucket LDS counting sort -> THREE CONTIGUOUS
//                         spack ranges -> all global writes coalesced full lines.
// -----------------------------------------------------------------------------
__global__ void bucket_kernel(const int* __restrict__ fr, const int* __restrict__ fc,
                              const float* __restrict__ fv,
                              const int* __restrict__ a1r, const int* __restrict__ a1c,
                              const float* __restrict__ a1v,
                              const int* __restrict__ a2r, const int* __restrict__ a2c,
                              const float* __restrict__ a2v,
                              int* __restrict__ bcur,
                              unsigned* __restrict__ gpack,
                              unsigned short* __restrict__ gmeta) {
    __shared__ int cnt8[8];
    __shared__ int offc[8];              // exclusive scan of cnt8 (bucket starts)
    __shared__ int gbase[8];             // global append base per bucket
    __shared__ unsigned spk[768];        // staging, grouped by bucket
    __shared__ unsigned short smeta[768];
    int t = threadIdx.x;
    if (t < 8) cnt8[t] = 0;
    __syncthreads();

    int e = blockIdx.x * 256 + t;        // NNZ = 3125 * 256, no tail
    int r[3]; unsigned pk[3]; int loc[3]; int pb[3];
    r[0] = __builtin_nontemporal_load(&fr[e]);
    pk[0] = pack_cv(__builtin_nontemporal_load(&fc[e]),
                    __builtin_nontemporal_load(&fv[e]));
    r[1] = __builtin_nontemporal_load(&a1r[e]);
    pk[1] = pack_cv(__builtin_nontemporal_load(&a1c[e]),
                    __builtin_nontemporal_load(&a1v[e]));
    r[2] = __builtin_nontemporal_load(&a2r[e]);
    pk[2] = pack_cv(__builtin_nontemporal_load(&a2c[e]),
                    __builtin_nontemporal_load(&a2v[e]));
#pragma unroll
    for (int s = 0; s < 3; ++s) {
        pb[s] = r[s] / PART_W;
        loc[s] = atomicAdd(&cnt8[pb[s]], 1);
    }
    __syncthreads();
    if (t < 8) gbase[t] = atomicAdd(&bcur[t], cnt8[t]);
    if (t == 0) {
        int acc = 0;
#pragma unroll
        for (int q = 0; q < 8; ++q) { offc[q] = acc; acc += cnt8[q]; }
    }
    __syncthreads();
#pragma unroll
    for (int s = 0; s < 3; ++s) {
        int pos = offc[pb[s]] + loc[s];
        spk[pos] = pk[s];
        smeta[pos] = (unsigned short)((s << 13) | (r[s] - pb[s] * PART_W));
    }
    __syncthreads();
#pragma unroll
    for (int k = 0; k < 3; ++k) {
        int i = t + k * 256;
        int q = 0;
#pragma unroll
        for (int b = 1; b < 8; ++b) q += (i >= offc[b]);
        int g = q * BCAP + gbase[q] + (i - offc[q]);
        gpack[g] = spk[i];
        gmeta[g] = smeta[i];
    }
}

// Pass B: partition bucket -> 64 sub-buckets (98-row ranges). blockIdx&7 = p.
__global__ void subbucket_kernel(const unsigned* __restrict__ gpack1,
                                 const unsigned short* __restrict__ gmeta1,
                                 const int* __restrict__ bcur,
                                 int* __restrict__ subcur,
                                 unsigned* __restrict__ gpack2,
                                 unsigned short* __restrict__ gmeta2) {
    int p = blockIdx.x & (NPART - 1);
    int chunk = blockIdx.x >> 3;
    int base = chunk * ENT_B;
    int n = bcur[p];
    int cnt = n - base;
    if (cnt <= 0) return;                // uniform across block
    if (cnt > ENT_B) cnt = ENT_B;
    __shared__ int c64[NSUB], off[NSUB], gb[NSUB];
    __shared__ unsigned spk[ENT_B];
    __shared__ unsigned short smt[ENT_B];
    int t = threadIdx.x;
    if (t < NSUB) c64[t] = 0;
    __syncthreads();
    unsigned pk[16]; unsigned short mt[16]; int loc[16]; int sb[16];
#pragma unroll
    for (int k = 0; k < 16; ++k) {
        int i = t + k * 256;
        if (i < cnt) {
            pk[k] = gpack1[p * BCAP + base + i];
            mt[k] = gmeta1[p * BCAP + base + i];
            sb[k] = (int)(mt[k] & 8191u) / SUBW;
            loc[k] = atomicAdd(&c64[sb[k]], 1);
        } else sb[k] = -1;
    }
    __syncthreads();
    if (t == 0) {
        int a = 0;
#pragma unroll
        for (int q = 0; q < NSUB; ++q) { off[q] = a; a += c64[q]; }
    }
    __syncthreads();
    if (t < NSUB && c64[t] > 0) gb[t] = atomicAdd(&subcur[p * NSUB + t], c64[t]);
    __syncthreads();
#pragma unroll
    for (int k = 0; k < 16; ++k) {
        if (sb[k] >= 0) {
            int pos = off[sb[k]] + loc[k];
            spk[pos] = pk[k];
            smt[pos] = mt[k];
        }
    }
    __syncthreads();
    // Coalesced write-out: ~64-entry contiguous chunks per sub-bucket.
    for (int i = t; i < cnt; i += 256) {
        unsigned short m = smt[i];
        int s2 = (int)(m & 8191u) / SUBW;
        int g = (p * NSUB + s2) * SUBCAP + gb[s2] + (i - off[s2]);
        gpack2[g] = spk[i];
        gmeta2[g] = m;
    }
}

// Pass C1: per-sub-bucket histogram -> cnt (plain stores, covers all of cnt).
__global__ __launch_bounds__(512) void subhist_kernel(
        const unsigned short* __restrict__ gmeta2,
        const int* __restrict__ subcur,
        int* __restrict__ cnt) {
    int p = blockIdx.x & (NPART - 1);
    int sub = blockIdx.x >> 3;
    int n = subcur[p * NSUB + sub];
    __shared__ int h[512];
    int t = threadIdx.x;
    h[t] = 0;
    __syncthreads();
    long base = (long)(p * NSUB + sub) * SUBCAP;
    for (int i = t; i < n; i += 512) {
        unsigned short m = gmeta2[base + i];
        int key = (int)(m >> 13) * SUBW + ((int)(m & 8191u) - sub * SUBW);
        atomicAdd(&h[key], 1);
    }
    __syncthreads();
    if (t < 3 * SUBW) {
        int s = t / SUBW, d = t - s * SUBW;
        int rl = sub * SUBW + d;
        if (rl < PART_W) cnt[s * N_NODES + p * PART_W + rl] = h[t];
    }
}

__global__ void scan_block_kernel(const int* __restrict__ cnt,
                                  int* __restrict__ starts,
                                  int* __restrict__ bsum) {
    __shared__ int tmp[256];
    int g = blockIdx.x * 256 + threadIdx.x;
    int v = (g < SCAN_N) ? cnt[g] : 0;
    tmp[threadIdx.x] = v;
    __syncthreads();
    for (int off = 1; off < 256; off <<= 1) {
        int t = (threadIdx.x >= off) ? tmp[threadIdx.x - off] : 0;
        __syncthreads();
        tmp[threadIdx.x] += t;
        __syncthreads();
    }
    int incl = tmp[threadIdx.x];
    if (g < SCAN_N) starts[g] = incl - v;          // exclusive
    if (threadIdx.x == 255) bsum[blockIdx.x] = incl;
}

__global__ void scan_bsum_kernel(int* __restrict__ bsum, int nb) {
    __shared__ int tmp[1024];
    int t = threadIdx.x;
    int v = (t < nb) ? bsum[t] : 0;
    tmp[t] = v;
    __syncthreads();
    for (int off = 1; off < 1024; off <<= 1) {
        int x = (t >= off) ? tmp[t - off] : 0;
        __syncthreads();
        tmp[t] += x;
        __syncthreads();
    }
    if (t < nb) bsum[t] = tmp[t] - v;              // exclusive block offsets
}

__global__ void scan_add_kernel(int* __restrict__ starts,
                                const int* __restrict__ bsum) {
    int g = blockIdx.x * 256 + threadIdx.x;
    if (g < SCAN_N) starts[g] += bsum[blockIdx.x];
}

// Pass C2: LDS counting sort of one sub-bucket, then coalesced contiguous
// writes into spack (three contiguous global ranges, one per segment).
__global__ __launch_bounds__(512) void sort_write_kernel(
        const unsigned* __restrict__ gpack2,
        const unsigned short* __restrict__ gmeta2,
        const int* __restrict__ subcur,
        const int* __restrict__ starts,
        unsigned* __restrict__ spack) {
    int p = blockIdx.x & (NPART - 1);
    int sub = blockIdx.x >> 3;
    int n = subcur[p * NSUB + sub];
    __shared__ int h[512];
    __shared__ int e[512];
    __shared__ int cur[512];
    __shared__ unsigned sorted[SUBCAP];
    int t = threadIdx.x;
    h[t] = 0;
    __syncthreads();
    long base = (long)(p * NSUB + sub) * SUBCAP;
    unsigned pk[12]; short ky[12];
#pragma unroll
    for (int k = 0; k < 12; ++k) {           // SUBCAP = 12*512 exactly
        int i = t + k * 512;
        if (i < n) {
            pk[k] = gpack2[base + i];
            unsigned short m = gmeta2[base + i];
            int key = (int)(m >> 13) * SUBW + ((int)(m & 8191u) - sub * SUBW);
            ky[k] = (short)key;
            atomicAdd(&h[key], 1);
        } else ky[k] = -1;
    }
    __syncthreads();
    e[t] = h[t];
    __syncthreads();
    for (int off = 1; off < 512; off <<= 1) {
        int v = (t >= off) ? e[t - off] : 0;
        __syncthreads();
        e[t] += v;
        __syncthreads();
    }
    int excl = e[t] - h[t];
    __syncthreads();
    e[t] = excl;
    cur[t] = excl;
    __syncthreads();
#pragma unroll
    for (int k = 0; k < 12; ++k) {
        if (ky[k] >= 0) {
            int pos = atomicAdd(&cur[ky[k]], 1);
            sorted[pos] = pk[k];
        }
    }
    __syncthreads();
    int s1 = e[SUBW];                         // local start of adj1 entries
    int s2 = e[2 * SUBW];                     // local start of adj2 entries
    int rb = p * PART_W + sub * SUBW;
    int gb0 = starts[rb];
    int gb1 = starts[N_NODES + rb];
    int gb2 = starts[2 * N_NODES + rb];
#pragma unroll
    for (int k = 0; k < 12; ++k) {
        int i = t + k * 512;
        if (i < n) {
            unsigned v = sorted[i];
            int dst;
            if (i < s1)      dst = gb0 + i;
            else if (i < s2) dst = gb1 + (i - s1);
            else             dst = gb2 + (i - s2);
            spack[dst] = v;
        }
    }
}

// -----------------------------------------------------------------------------
// Phase 1: per-row gather  xw{1,2}[r,:] = sum_e v_e * W{1,2}[c_e,:]
// 32-lane row group, shfl-broadcast, 8-deep unroll. Output written in the
// SLICE-MAJOR fp16 layout consumed by adj_gather_sliced:
//   xw[s][r][d16]  (s = dim/16 in [0,8), 32 B per row-slice, slice = 1.6 MB).
// Lane l holds dims [4l,4l+4) = slice l>>2, quarter l&3.
// -----------------------------------------------------------------------------
__global__ void feat_gather_kernel(const int* __restrict__ starts,
                                   const unsigned* __restrict__ spack,
                                   const float4* __restrict__ W1,
                                   const float4* __restrict__ W2,
                                   ushort4* __restrict__ xw1s,
                                   ushort4* __restrict__ xw2s) {
    int lane = threadIdx.x & 31;
    int sub  = threadIdx.x >> 5;
    int r = blockIdx.x * 8 + sub;
    if (r >= N_NODES) return;
    int s = starts[r];
    int e = starts[r + 1];            // starts[50000] == 800000 (adj1 base)
    float4 a1 = make_float4(0.f, 0.f, 0.f, 0.f);
    float4 a2 = make_float4(0.f, 0.f, 0.f, 0.f);
    for (int base = s; base < e; base += 32) {
        int n = e - base;
        int m = (n < 32) ? n : 32;
        unsigned pk = (lane < m) ? spack[base + lane] : 0u;
        int j = 0;
        for (; j + 7 < m; j += 8) {
            unsigned pp[8]; float4 w1v[8]; float4 w2v[8];
#pragma unroll
            for (int k = 0; k < 8; ++k) pp[k] = __shfl(pk, j + k, 32);
#pragma unroll
            for (int k = 0; k < 8; ++k) {
                int c = upk_c(pp[k]);
                w1v[k] = W1[c * 32 + lane];
                w2v[k] = W2[c * 32 + lane];
            }
#pragma unroll
            for (int k = 0; k < 8; ++k) {
                float v = upk_v(pp[k]);
                a1.x += v * w1v[k].x; a1.y += v * w1v[k].y;
                a1.z += v * w1v[k].z; a1.w += v * w1v[k].w;
                a2.x += v * w2v[k].x; a2.y += v * w2v[k].y;
                a2.z += v * w2v[k].z; a2.w += v * w2v[k].w;
            }
        }
        for (; j + 3 < m; j += 4) {
            unsigned pp[4]; float4 w1v[4]; float4 w2v[4];
#pragma unroll
            for (int k = 0; k < 4; ++k) pp[k] = __shfl(pk, j + k, 32);
#pragma unroll
            for (int k = 0; k < 4; ++k) {
                int c = upk_c(pp[k]);
                w1v[k] = W1[c * 32 + lane];
                w2v[k] = W2[c * 32 + lane];
            }
#pragma unroll
            for (int k = 0; k < 4; ++k) {
                float v = upk_v(pp[k]);
                a1.x += v * w1v[k].x; a1.y += v * w1v[k].y;
                a1.z += v * w1v[k].z; a1.w += v * w1v[k].w;
                a2.x += v * w2v[k].x; a2.y += v * w2v[k].y;
                a2.z += v * w2v[k].z; a2.w += v * w2v[k].w;
            }
        }
        for (; j < m; ++j) {
            unsigned pj = __shfl(pk, j, 32);
            int c = upk_c(pj);
            float v = upk_v(pj);
            float4 w1 = W1[c * 32 + lane];
            float4 w2 = W2[c * 32 + lane];
            a1.x += v * w1.x; a1.y += v * w1.y; a1.z += v * w1.z; a1.w += v * w1.w;
            a2.x += v * w2.x; a2.y += v * w2.y; a2.z += v * w2.z; a2.w += v * w2.w;
        }
    }
    ushort4 q1, q2;
    q1.x = __half_as_ushort(__float2half(a1.x)); q1.y = __half_as_ushort(__float2half(a1.y));
    q1.z = __half_as_ushort(__float2half(a1.z)); q1.w = __half_as_ushort(__float2half(a1.w));
    q2.x = __half_as_ushort(__float2half(a2.x)); q2.y = __half_as_ushort(__float2half(a2.y));
    q2.z = __half_as_ushort(__float2half(a2.z)); q2.w = __half_as_ushort(__float2half(a2.w));
    // Slice-major store: lanes {4k..4k+3} of both waves' rows hit the same
    // 64 B line per slice (rows r, r+1 adjacent) -> full-line writes.
    size_t idx = (size_t)(lane >> 2) * (N_NODES * 4) + (size_t)r * 4 + (lane & 3);
    xw1s[idx] = q1;
    xw2s[idx] = q2;
}

// -----------------------------------------------------------------------------
// Phase 2 (dim-sliced): out[r, 16s:16s+16] = relu( sum_adj v * xw[s][c][:] )
// blockIdx&7 = slice = XCD (dispatch round-robin): each XCD's gathers hit only
// its 3.2 MB slice pair -> L2-RESIDENT. The old layout missed L2 on nearly
// every 256 B row gather (working set 25.6 MB >> 4 MB L2): FETCH was 246 MB
// ~= 8 XCDs x full tables. Now xw is fetched from HBM once (~26 MB compulsory);
// spack re-read x8 (51 MB) is L3-absorbed and nt-hinted to spare L2.
// 4-lane group per row: 8 edges/iter zero-padded (pack 0 -> v=0, exact),
// 8 independent 32 B gathers in flight, fp32 acc of 4 dims/lane.
// -----------------------------------------------------------------------------
__global__ void adj_gather_sliced(const int* __restrict__ starts,
                                  const unsigned* __restrict__ spack,
                                  const ushort4* __restrict__ xw1s,
                                  const ushort4* __restrict__ xw2s,
                                  vf4* __restrict__ out) {
    int s  = blockIdx.x & (NSLICE - 1);
    int rc = blockIdx.x >> 3;
    int g  = threadIdx.x >> 2;          // 64 row-groups per block
    int q  = threadIdx.x & 3;
    int r  = rc * 64 + g;
    bool valid = (r < N_NODES);
    vf4 acc = {0.f, 0.f, 0.f, 0.f};
    const ushort4* __restrict__ sl1 = xw1s + (size_t)s * (N_NODES * 4);
    const ushort4* __restrict__ sl2 = xw2s + (size_t)s * (N_NODES * 4);

    for (int rel = 0; rel < 2; ++rel) {
        int st = 0, en = 0;
        if (valid) {
            st = starts[(1 + rel) * N_NODES + r];
            en = (rel == 1 && r == N_NODES - 1) ? TOTAL_NNZ
                                                : starts[(1 + rel) * N_NODES + r + 1];
        }
        const ushort4* __restrict__ sl = (rel == 0) ? sl1 : sl2;
        for (int base = st; base < en; base += 8) {
            int m = en - base;
            // zero-padded 8-wide chunk: pack 0 -> c=0 (safe addr), v=0 (exact)
            unsigned pk0 = (q < m)     ? __builtin_nontemporal_load(&spack[base + q])     : 0u;
            unsigned pk1 = (4 + q < m) ? __builtin_nontemporal_load(&spack[base + 4 + q]) : 0u;
            unsigned pp[8];
#pragma unroll
            for (int k = 0; k < 4; ++k) pp[k]     = __shfl(pk0, k, 4);
#pragma unroll
            for (int k = 0; k < 4; ++k) pp[4 + k] = __shfl(pk1, k, 4);
            ushort4 xx[8];
#pragma unroll
            for (int k = 0; k < 8; ++k) xx[k] = sl[upk_c(pp[k]) * 4 + q];
#pragma unroll
            for (int k = 0; k < 8; ++k) {
                float v = upk_v(pp[k]);
                acc.x += v * h2f(xx[k].x); acc.y += v * h2f(xx[k].y);
                acc.z += v * h2f(xx[k].z); acc.w += v * h2f(xx[k].w);
            }
        }
    }
    if (valid) {
        vf4 res;
        res.x = fmaxf(acc.x, 0.f); res.y = fmaxf(acc.y, 0.f);
        res.z = fmaxf(acc.z, 0.f); res.w = fmaxf(acc.w, 0.f);
        __builtin_nontemporal_store(res, &out[(size_t)r * 32 + s * 4 + q]);
    }
}

extern "C" void kernel_launch(void* const* d_in, const int* in_sizes, int n_in,
                              void* d_out, int out_size, void* d_ws, size_t ws_size,
                              hipStream_t stream) {
    const int*   feat_row  = (const int*)  d_in[0];
    const int*   feat_col  = (const int*)  d_in[1];
    const float* feat_vals = (const float*)d_in[2];
    const int*   adj1_row  = (const int*)  d_in[3];
    const int*   adj1_col  = (const int*)  d_in[4];
    const float* adj1_vals = (const float*)d_in[5];
    const int*   adj2_row  = (const int*)  d_in[6];
    const int*   adj2_col  = (const int*)  d_in[7];
    const float* adj2_vals = (const float*)d_in[8];
    const float* W1        = (const float*)d_in[9];
    const float* W2        = (const float*)d_in[10];

    // Workspace layout. Bucket storage (~33.8 MB) is dead after sort_write,
    // so xw1s/xw2s (25.6 MB) alias it. Total footprint ~44.6 MB.
    char* ws = (char*)d_ws;
    unsigned* spack = (unsigned*)ws;            ws += (size_t)TOTAL_NNZ * 4;          // 9.6 MB
    int*      cnt   = (int*)ws;                 ws += (size_t)SCAN_N * 4;             // 600 KB
    int*      starts= (int*)ws;                 ws += (size_t)SCAN_N * 4;             // 600 KB
    int*      bsum  = (int*)ws;                 ws += 1024 * 4;
    int*      bcur  = (int*)ws;                 ws += 16 * 4;                         // 8 used
    int*      subcur= (int*)ws;                 ws += (size_t)NPART * NSUB * 4;       // 2 KB
    char*     bkt   = ws;                                                             // bucket region
    unsigned* gpack1 = (unsigned*)bkt;
    unsigned short* gmeta1 = (unsigned short*)(bkt + (size_t)NPART * BCAP * 4);
    unsigned* gpack2 = (unsigned*)(bkt + (size_t)NPART * BCAP * 6);
    unsigned short* gmeta2 = (unsigned short*)(bkt + (size_t)NPART * BCAP * 6
                                                  + (size_t)NPART * NSUB * SUBCAP * 4);
    ushort4*  xw1s  = (ushort4*)bkt;                                     // alias (after C2)
    ushort4*  xw2s  = (ushort4*)(bkt + (size_t)N_NODES * OUT_DIM * 2);   // alias

    // Zero only bcur + subcur (adjacent, 528 ints). cnt is fully written by C1.
    (void)hipMemsetAsync(bcur, 0, (16 + NPART * NSUB) * sizeof(int), stream);

    const int block = 256;

    // A: single read of all 9 streams, LDS-bucket by row partition.
    bucket_kernel<<<NNZ / block, block, 0, stream>>>(
        feat_row, feat_col, feat_vals,
        adj1_row, adj1_col, adj1_vals,
        adj2_row, adj2_col, adj2_vals,
        bcur, gpack1, gmeta1);

    // B: partition bucket -> 64 sub-buckets (XCD-local reads, blockIdx&7 = p).
    subbucket_kernel<<<NPART * BBLK_B, block, 0, stream>>>(
        gpack1, gmeta1, bcur, subcur, gpack2, gmeta2);

    // C1: per-sub-bucket histogram -> cnt (no atomics, covers all slots).
    subhist_kernel<<<NPART * NSUB, 512, 0, stream>>>(gmeta2, subcur, cnt);

    scan_block_kernel<<<SCAN_BLOCKS, 256, 0, stream>>>(cnt, starts, bsum);
    scan_bsum_kernel<<<1, 1024, 0, stream>>>(bsum, SCAN_BLOCKS);
    scan_add_kernel<<<SCAN_BLOCKS, 256, 0, stream>>>(starts, bsum);

    // C2: LDS counting sort per sub-bucket, contiguous coalesced spack writes.
    sort_write_kernel<<<NPART * NSUB, 512, 0, stream>>>(
        gpack2, gmeta2, subcur, starts, spack);

    const int grid_rows = N_NODES / 8;                           // 6250 blocks, 8 rows each
    feat_gather_kernel<<<grid_rows, 256, 0, stream>>>(
        starts, spack, (const float4*)W1, (const float4*)W2, xw1s, xw2s);

    // Dim-sliced adj gather: blockIdx&7 = slice = XCD.
    adj_gather_sliced<<<NSLICE * ADJ_RC, 256, 0, stream>>>(
        starts, spack, xw1s, xw2s, (vf4*)d_out);
}

// Round 7
// 273.334 us; speedup vs baseline: 1.1595x; 1.1595x over previous
//
#include <hip/hip_runtime.h>
#include <hip/hip_fp16.h>

// Problem constants (fixed by the reference setup)
#define N_NODES 50000
#define IN_DIM 256
#define OUT_DIM 128
#define NNZ 800000          // nnz for feat, adj1, adj2 each
#define SCAN_N (3 * N_NODES)        // 150000 row counters (feat | adj1 | adj2)
#define TOTAL_NNZ (3 * NNZ)         // 2.4M sorted entries
#define SCAN_BLOCKS ((SCAN_N + 255) / 256)   // 586
#define NPART 8                      // one row-partition per XCD
#define PART_W (N_NODES / NPART)     // 6250 rows per partition

// Level-1 per-partition bucket capacity.
// Expected 2.4M/8 = 300000, sigma ~512; 310016 = +19.6 sigma, multiple of 256.
#define BCAP 310016

// Level-2 sub-buckets: 64 per partition, 98 rows each (64*98=6272 >= 6250).
// Expected entries 2.4M*98/50000 = 4704, sigma ~68; 6144 = +21 sigma = 12*512.
#define NSUB 64
#define SUBW 98
#define SUBCAP 6144
#define ENT_B 4096                   // entries per subbucket_kernel block (256 thr x 16)
#define BBLK_B ((BCAP + ENT_B - 1) / ENT_B)   // 76 blocks per partition

// adj_gather dim-slicing: 8 slices of 16 output dims; slice s pinned to XCD s
// via blockIdx&7. Per-XCD working set = 2 tables x 50000 x 32 B = 3.2 MB < 4 MB L2.
#define NSLICE 8
#define ADJ_RC ((N_NODES + 63) / 64)  // 782 row-chunks of 64 rows

// Native clang vector types — __builtin_nontemporal_* requires these.
typedef float vf4 __attribute__((ext_vector_type(4)));

// Packed entry: [col:16 | fp16(val):16].  adj cols < 50000 < 65536, feat cols < 256.
static __device__ __forceinline__ unsigned pack_cv(int c, float v) {
    return ((unsigned)c << 16) | (unsigned)__half_as_ushort(__float2half(v));
}
static __device__ __forceinline__ int   upk_c(unsigned pk) { return (int)(pk >> 16); }
static __device__ __forceinline__ float upk_v(unsigned pk) {
    return __half2float(__ushort_as_half((unsigned short)(pk & 0xffffu)));
}
static __device__ __forceinline__ float h2f(unsigned short h) {
    return __half2float(__ushort_as_half(h));
}

// -----------------------------------------------------------------------------
// CSR build, three-level counting sort (KNOWN-GOOD round-2 pipeline):
//   A (bucket_kernel):    read every edge once, LDS-group by partition (row/6250),
//                         append chunks (~96 entries) to per-partition buckets.
//   B (subbucket_kernel): partition bucket -> 64 sub-buckets (98-row ranges).
//   C1 (subhist_kernel):  per-sub-bucket LDS histogram -> cnt (plain stores).
//   scan:                 global exclusive scan over 150K counters -> starts.
//   C2 (sort_write_kernel): per-sub-bucket LDS counting sort -> THREE CONTIGUOUS
//                         spack ranges -> all global writes coalesced full lines.
// -----------------------------------------------------------------------------
__global__ void bucket_kernel(const int* __restrict__ fr, const int* __restrict__ fc,
                              const float* __restrict__ fv,
                              const int* __restrict__ a1r, const int* __restrict__ a1c,
                              const float* __restrict__ a1v,
                              const int* __restrict__ a2r, const int* __restrict__ a2c,
                              const float* __restrict__ a2v,
                              int* __restrict__ bcur,
                              unsigned* __restrict__ gpack,
                              unsigned short* __restrict__ gmeta) {
    __shared__ int cnt8[8];
    __shared__ int offc[8];              // exclusive scan of cnt8 (bucket starts)
    __shared__ int gbase[8];             // global append base per bucket
    __shared__ unsigned spk[768];        // staging, grouped by bucket
    __shared__ unsigned short smeta[768];
    int t = threadIdx.x;
    if (t < 8) cnt8[t] = 0;
    __syncthreads();

    int e = blockIdx.x * 256 + t;        // NNZ = 3125 * 256, no tail
    int r[3]; unsigned pk[3]; int loc[3]; int pb[3];
    r[0] = __builtin_nontemporal_load(&fr[e]);
    pk[0] = pack_cv(__builtin_nontemporal_load(&fc[e]),
                    __builtin_nontemporal_load(&fv[e]));
    r[1] = __builtin_nontemporal_load(&a1r[e]);
    pk[1] = pack_cv(__builtin_nontemporal_load(&a1c[e]),
                    __builtin_nontemporal_load(&a1v[e]));
    r[2] = __builtin_nontemporal_load(&a2r[e]);
    pk[2] = pack_cv(__builtin_nontemporal_load(&a2c[e]),
                    __builtin_nontemporal_load(&a2v[e]));
#pragma unroll
    for (int s = 0; s < 3; ++s) {
        pb[s] = r[s] / PART_W;
        loc[s] = atomicAdd(&cnt8[pb[s]], 1);
    }
    __syncthreads();
    if (t < 8) gbase[t] = atomicAdd(&bcur[t], cnt8[t]);
    if (t == 0) {
        int acc = 0;
#pragma unroll
        for (int q = 0; q < 8; ++q) { offc[q] = acc; acc += cnt8[q]; }
    }
    __syncthreads();
#pragma unroll
    for (int s = 0; s < 3; ++s) {
        int pos = offc[pb[s]] + loc[s];
        spk[pos] = pk[s];
        smeta[pos] = (unsigned short)((s << 13) | (r[s] - pb[s] * PART_W));
    }
    __syncthreads();
#pragma unroll
    for (int k = 0; k < 3; ++k) {
        int i = t + k * 256;
        int q = 0;
#pragma unroll
        for (int b = 1; b < 8; ++b) q += (i >= offc[b]);
        int g = q * BCAP + gbase[q] + (i - offc[q]);
        gpack[g] = spk[i];
        gmeta[g] = smeta[i];
    }
}

// Pass B: partition bucket -> 64 sub-buckets (98-row ranges). blockIdx&7 = p.
__global__ void subbucket_kernel(const unsigned* __restrict__ gpack1,
                                 const unsigned short* __restrict__ gmeta1,
                                 const int* __restrict__ bcur,
                                 int* __restrict__ subcur,
                                 unsigned* __restrict__ gpack2,
                                 unsigned short* __restrict__ gmeta2) {
    int p = blockIdx.x & (NPART - 1);
    int chunk = blockIdx.x >> 3;
    int base = chunk * ENT_B;
    int n = bcur[p];
    int cnt = n - base;
    if (cnt <= 0) return;                // uniform across block
    if (cnt > ENT_B) cnt = ENT_B;
    __shared__ int c64[NSUB], off[NSUB], gb[NSUB];
    __shared__ unsigned spk[ENT_B];
    __shared__ unsigned short smt[ENT_B];
    int t = threadIdx.x;
    if (t < NSUB) c64[t] = 0;
    __syncthreads();
    unsigned pk[16]; unsigned short mt[16]; int loc[16]; int sb[16];
#pragma unroll
    for (int k = 0; k < 16; ++k) {
        int i = t + k * 256;
        if (i < cnt) {
            pk[k] = gpack1[p * BCAP + base + i];
            mt[k] = gmeta1[p * BCAP + base + i];
            sb[k] = (int)(mt[k] & 8191u) / SUBW;
            loc[k] = atomicAdd(&c64[sb[k]], 1);
        } else sb[k] = -1;
    }
    __syncthreads();
    if (t == 0) {
        int a = 0;
#pragma unroll
        for (int q = 0; q < NSUB; ++q) { off[q] = a; a += c64[q]; }
    }
    __syncthreads();
    if (t < NSUB && c64[t] > 0) gb[t] = atomicAdd(&subcur[p * NSUB + t], c64[t]);
    __syncthreads();
#pragma unroll
    for (int k = 0; k < 16; ++k) {
        if (sb[k] >= 0) {
            int pos = off[sb[k]] + loc[k];
            spk[pos] = pk[k];
            smt[pos] = mt[k];
        }
    }
    __syncthreads();
    // Coalesced write-out: ~64-entry contiguous chunks per sub-bucket.
    for (int i = t; i < cnt; i += 256) {
        unsigned short m = smt[i];
        int s2 = (int)(m & 8191u) / SUBW;
        int g = (p * NSUB + s2) * SUBCAP + gb[s2] + (i - off[s2]);
        gpack2[g] = spk[i];
        gmeta2[g] = m;
    }
}

// Pass C1: per-sub-bucket histogram -> cnt (plain stores, covers all of cnt).
__global__ __launch_bounds__(512) void subhist_kernel(
        const unsigned short* __restrict__ gmeta2,
        const int* __restrict__ subcur,
        int* __restrict__ cnt) {
    int p = blockIdx.x & (NPART - 1);
    int sub = blockIdx.x >> 3;
    int n = subcur[p * NSUB + sub];
    __shared__ int h[512];
    int t = threadIdx.x;
    h[t] = 0;
    __syncthreads();
    long base = (long)(p * NSUB + sub) * SUBCAP;
    for (int i = t; i < n; i += 512) {
        unsigned short m = gmeta2[base + i];
        int key = (int)(m >> 13) * SUBW + ((int)(m & 8191u) - sub * SUBW);
        atomicAdd(&h[key], 1);
    }
    __syncthreads();
    if (t < 3 * SUBW) {
        int s = t / SUBW, d = t - s * SUBW;
        int rl = sub * SUBW + d;
        if (rl < PART_W) cnt[s * N_NODES + p * PART_W + rl] = h[t];
    }
}

__global__ void scan_block_kernel(const int* __restrict__ cnt,
                                  int* __restrict__ starts,
                                  int* __restrict__ bsum) {
    __shared__ int tmp[256];
    int g = blockIdx.x * 256 + threadIdx.x;
    int v = (g < SCAN_N) ? cnt[g] : 0;
    tmp[threadIdx.x] = v;
    __syncthreads();
    for (int off = 1; off < 256; off <<= 1) {
        int t = (threadIdx.x >= off) ? tmp[threadIdx.x - off] : 0;
        __syncthreads();
        tmp[threadIdx.x] += t;
        __syncthreads();
    }
    int incl = tmp[threadIdx.x];
    if (g < SCAN_N) starts[g] = incl - v;          // exclusive
    if (threadIdx.x == 255) bsum[blockIdx.x] = incl;
}

__global__ void scan_bsum_kernel(int* __restrict__ bsum, int nb) {
    __shared__ int tmp[1024];
    int t = threadIdx.x;
    int v = (t < nb) ? bsum[t] : 0;
    tmp[t] = v;
    __syncthreads();
    for (int off = 1; off < 1024; off <<= 1) {
        int x = (t >= off) ? tmp[t - off] : 0;
        __syncthreads();
        tmp[t] += x;
        __syncthreads();
    }
    if (t < nb) bsum[t] = tmp[t] - v;              // exclusive block offsets
}

__global__ void scan_add_kernel(int* __restrict__ starts,
                                const int* __restrict__ bsum) {
    int g = blockIdx.x * 256 + threadIdx.x;
    if (g < SCAN_N) starts[g] += bsum[blockIdx.x];
}

// Pass C2: LDS counting sort of one sub-bucket, then coalesced contiguous
// writes into spack (three contiguous global ranges, one per segment).
__global__ __launch_bounds__(512) void sort_write_kernel(
        const unsigned* __restrict__ gpack2,
        const unsigned short* __restrict__ gmeta2,
        const int* __restrict__ subcur,
        const int* __restrict__ starts,
        unsigned* __restrict__ spack) {
    int p = blockIdx.x & (NPART - 1);
    int sub = blockIdx.x >> 3;
    int n = subcur[p * NSUB + sub];
    __shared__ int h[512];
    __shared__ int e[512];
    __shared__ int cur[512];
    __shared__ unsigned sorted[SUBCAP];
    int t = threadIdx.x;
    h[t] = 0;
    __syncthreads();
    long base = (long)(p * NSUB + sub) * SUBCAP;
    unsigned pk[12]; short ky[12];
#pragma unroll
    for (int k = 0; k < 12; ++k) {           // SUBCAP = 12*512 exactly
        int i = t + k * 512;
        if (i < n) {
            pk[k] = gpack2[base + i];
            unsigned short m = gmeta2[base + i];
            int key = (int)(m >> 13) * SUBW + ((int)(m & 8191u) - sub * SUBW);
            ky[k] = (short)key;
            atomicAdd(&h[key], 1);
        } else ky[k] = -1;
    }
    __syncthreads();
    e[t] = h[t];
    __syncthreads();
    for (int off = 1; off < 512; off <<= 1) {
        int v = (t >= off) ? e[t - off] : 0;
        __syncthreads();
        e[t] += v;
        __syncthreads();
    }
    int excl = e[t] - h[t];
    __syncthreads();
    e[t] = excl;
    cur[t] = excl;
    __syncthreads();
#pragma unroll
    for (int k = 0; k < 12; ++k) {
        if (ky[k] >= 0) {
            int pos = atomicAdd(&cur[ky[k]], 1);
            sorted[pos] = pk[k];
        }
    }
    __syncthreads();
    int s1 = e[SUBW];                         // local start of adj1 entries
    int s2 = e[2 * SUBW];                     // local start of adj2 entries
    int rb = p * PART_W + sub * SUBW;
    int gb0 = starts[rb];
    int gb1 = starts[N_NODES + rb];
    int gb2 = starts[2 * N_NODES + rb];
#pragma unroll
    for (int k = 0; k < 12; ++k) {
        int i = t + k * 512;
        if (i < n) {
            unsigned v = sorted[i];
            int dst;
            if (i < s1)      dst = gb0 + i;
            else if (i < s2) dst = gb1 + (i - s1);
            else             dst = gb2 + (i - s2);
            spack[dst] = v;
        }
    }
}

// -----------------------------------------------------------------------------
// Phase 1: per-row gather  xw{1,2}[r,:] = sum_e v_e * W{1,2}[c_e,:]
// 32-lane row group, shfl-broadcast, 8-deep unroll. Output written in the
// SLICE-MAJOR fp16 layout consumed by adj_gather_sliced:
//   xw[s][r][d16]  (s = dim/16 in [0,8), 32 B per row-slice, slice = 1.6 MB).
// Lane l holds dims [4l,4l+4) = slice l>>2, quarter l&3.
// -----------------------------------------------------------------------------
__global__ void feat_gather_kernel(const int* __restrict__ starts,
                                   const unsigned* __restrict__ spack,
                                   const float4* __restrict__ W1,
                                   const float4* __restrict__ W2,
                                   ushort4* __restrict__ xw1s,
                                   ushort4* __restrict__ xw2s) {
    int lane = threadIdx.x & 31;
    int sub  = threadIdx.x >> 5;
    int r = blockIdx.x * 8 + sub;
    if (r >= N_NODES) return;
    int s = starts[r];
    int e = starts[r + 1];            // starts[50000] == 800000 (adj1 base)
    float4 a1 = make_float4(0.f, 0.f, 0.f, 0.f);
    float4 a2 = make_float4(0.f, 0.f, 0.f, 0.f);
    for (int base = s; base < e; base += 32) {
        int n = e - base;
        int m = (n < 32) ? n : 32;
        unsigned pk = (lane < m) ? spack[base + lane] : 0u;
        int j = 0;
        for (; j + 7 < m; j += 8) {
            unsigned pp[8]; float4 w1v[8]; float4 w2v[8];
#pragma unroll
            for (int k = 0; k < 8; ++k) pp[k] = __shfl(pk, j + k, 32);
#pragma unroll
            for (int k = 0; k < 8; ++k) {
                int c = upk_c(pp[k]);
                w1v[k] = W1[c * 32 + lane];
                w2v[k] = W2[c * 32 + lane];
            }
#pragma unroll
            for (int k = 0; k < 8; ++k) {
                float v = upk_v(pp[k]);
                a1.x += v * w1v[k].x; a1.y += v * w1v[k].y;
                a1.z += v * w1v[k].z; a1.w += v * w1v[k].w;
                a2.x += v * w2v[k].x; a2.y += v * w2v[k].y;
                a2.z += v * w2v[k].z; a2.w += v * w2v[k].w;
            }
        }
        for (; j + 3 < m; j += 4) {
            unsigned pp[4]; float4 w1v[4]; float4 w2v[4];
#pragma unroll
            for (int k = 0; k < 4; ++k) pp[k] = __shfl(pk, j + k, 32);
#pragma unroll
            for (int k = 0; k < 4; ++k) {
                int c = upk_c(pp[k]);
                w1v[k] = W1[c * 32 + lane];
                w2v[k] = W2[c * 32 + lane];
            }
#pragma unroll
            for (int k = 0; k < 4; ++k) {
                float v = upk_v(pp[k]);
                a1.x += v * w1v[k].x; a1.y += v * w1v[k].y;
                a1.z += v * w1v[k].z; a1.w += v * w1v[k].w;
                a2.x += v * w2v[k].x; a2.y += v * w2v[k].y;
                a2.z += v * w2v[k].z; a2.w += v * w2v[k].w;
            }
        }
        for (; j < m; ++j) {
            unsigned pj = __shfl(pk, j, 32);
            int c = upk_c(pj);
            float v = upk_v(pj);
            float4 w1 = W1[c * 32 + lane];
            float4 w2 = W2[c * 32 + lane];
            a1.x += v * w1.x; a1.y += v * w1.y; a1.z += v * w1.z; a1.w += v * w1.w;
            a2.x += v * w2.x; a2.y += v * w2.y; a2.z += v * w2.z; a2.w += v * w2.w;
        }
    }
    ushort4 q1, q2;
    q1.x = __half_as_ushort(__float2half(a1.x)); q1.y = __half_as_ushort(__float2half(a1.y));
    q1.z = __half_as_ushort(__float2half(a1.z)); q1.w = __half_as_ushort(__float2half(a1.w));
    q2.x = __half_as_ushort(__float2half(a2.x)); q2.y = __half_as_ushort(__float2half(a2.y));
    q2.z = __half_as_ushort(__float2half(a2.z)); q2.w = __half_as_ushort(__float2half(a2.w));
    // Slice-major store: lanes {4k..4k+3} of both waves' rows hit the same
    // 64 B line per slice (rows r, r+1 adjacent) -> full-line writes.
    size_t idx = (size_t)(lane >> 2) * (N_NODES * 4) + (size_t)r * 4 + (lane & 3);
    xw1s[idx] = q1;
    xw2s[idx] = q2;
}

// -----------------------------------------------------------------------------
// Phase 2 (dim-sliced): out[r, 16s:16s+16] = relu( sum_adj v * xw[s][c][:] )
// blockIdx&7 = slice = XCD: per-XCD gather working set 3.2 MB -> L2-RESIDENT
// (CONFIRMED round 6: FETCH 246 -> 71 MB). Round-6 regression root cause:
// nt-hinted spack loads bypassed L2, putting an L3/HBM-latency load at the
// head of every 8-edge dependency chain. Fix: plain (L2-cached) spack loads +
// 16-edge spack prefetch per iteration (one latency exposure per 16 edges,
// second half's shuffles/gathers overlap first half's FMAs).
// 4-lane group per row: zero-padded (pack 0 -> v=0, exact), 8 gathers in
// flight, fp32 acc of 4 dims/lane.
// -----------------------------------------------------------------------------
__global__ void adj_gather_sliced(const int* __restrict__ starts,
                                  const unsigned* __restrict__ spack,
                                  const ushort4* __restrict__ xw1s,
                                  const ushort4* __restrict__ xw2s,
                                  vf4* __restrict__ out) {
    int s  = blockIdx.x & (NSLICE - 1);
    int rc = blockIdx.x >> 3;
    int g  = threadIdx.x >> 2;          // 64 row-groups per block
    int q  = threadIdx.x & 3;
    int r  = rc * 64 + g;
    bool valid = (r < N_NODES);
    vf4 acc = {0.f, 0.f, 0.f, 0.f};
    const ushort4* __restrict__ sl1 = xw1s + (size_t)s * (N_NODES * 4);
    const ushort4* __restrict__ sl2 = xw2s + (size_t)s * (N_NODES * 4);

    for (int rel = 0; rel < 2; ++rel) {
        int st = 0, en = 0;
        if (valid) {
            st = starts[(1 + rel) * N_NODES + r];
            en = (rel == 1 && r == N_NODES - 1) ? TOTAL_NNZ
                                                : starts[(1 + rel) * N_NODES + r + 1];
        }
        const ushort4* __restrict__ sl = (rel == 0) ? sl1 : sl2;
        for (int base = st; base < en; base += 16) {
            int m = en - base;
            // 16 edges of packs up front (L2-streamed, one latency exposure);
            // zero-padded: pack 0 -> c=0 (safe addr), v=0 (exact).
            unsigned pk0 = (q < m)      ? spack[base + q]      : 0u;
            unsigned pk1 = (4 + q < m)  ? spack[base + 4 + q]  : 0u;
            unsigned pk2 = (8 + q < m)  ? spack[base + 8 + q]  : 0u;
            unsigned pk3 = (12 + q < m) ? spack[base + 12 + q] : 0u;
            // half 1: edges 0..7
            {
                unsigned pp[8];
#pragma unroll
                for (int k = 0; k < 4; ++k) pp[k]     = __shfl(pk0, k, 4);
#pragma unroll
                for (int k = 0; k < 4; ++k) pp[4 + k] = __shfl(pk1, k, 4);
                ushort4 xx[8];
#pragma unroll
                for (int k = 0; k < 8; ++k) xx[k] = sl[upk_c(pp[k]) * 4 + q];
#pragma unroll
                for (int k = 0; k < 8; ++k) {
                    float v = upk_v(pp[k]);
                    acc.x += v * h2f(xx[k].x); acc.y += v * h2f(xx[k].y);
                    acc.z += v * h2f(xx[k].z); acc.w += v * h2f(xx[k].w);
                }
            }
            if (m <= 8) continue;
            // half 2: edges 8..15 (packs already resident)
            {
                unsigned pp[8];
#pragma unroll
                for (int k = 0; k < 4; ++k) pp[k]     = __shfl(pk2, k, 4);
#pragma unroll
                for (int k = 0; k < 4; ++k) pp[4 + k] = __shfl(pk3, k, 4);
                ushort4 xx[8];
#pragma unroll
                for (int k = 0; k < 8; ++k) xx[k] = sl[upk_c(pp[k]) * 4 + q];
#pragma unroll
                for (int k = 0; k < 8; ++k) {
                    float v = upk_v(pp[k]);
                    acc.x += v * h2f(xx[k].x); acc.y += v * h2f(xx[k].y);
                    acc.z += v * h2f(xx[k].z); acc.w += v * h2f(xx[k].w);
                }
            }
        }
    }
    if (valid) {
        vf4 res;
        res.x = fmaxf(acc.x, 0.f); res.y = fmaxf(acc.y, 0.f);
        res.z = fmaxf(acc.z, 0.f); res.w = fmaxf(acc.w, 0.f);
        __builtin_nontemporal_store(res, &out[(size_t)r * 32 + s * 4 + q]);
    }
}

extern "C" void kernel_launch(void* const* d_in, const int* in_sizes, int n_in,
                              void* d_out, int out_size, void* d_ws, size_t ws_size,
                              hipStream_t stream) {
    const int*   feat_row  = (const int*)  d_in[0];
    const int*   feat_col  = (const int*)  d_in[1];
    const float* feat_vals = (const float*)d_in[2];
    const int*   adj1_row  = (const int*)  d_in[3];
    const int*   adj1_col  = (const int*)  d_in[4];
    const float* adj1_vals = (const float*)d_in[5];
    const int*   adj2_row  = (const int*)  d_in[6];
    const int*   adj2_col  = (const int*)  d_in[7];
    const float* adj2_vals = (const float*)d_in[8];
    const float* W1        = (const float*)d_in[9];
    const float* W2        = (const float*)d_in[10];

    // Workspace layout. Bucket storage (~33.8 MB) is dead after sort_write,
    // so xw1s/xw2s (25.6 MB) alias it. Total footprint ~44.6 MB.
    char* ws = (char*)d_ws;
    unsigned* spack = (unsigned*)ws;            ws += (size_t)TOTAL_NNZ * 4;          // 9.6 MB
    int*      cnt   = (int*)ws;                 ws += (size_t)SCAN_N * 4;             // 600 KB
    int*      starts= (int*)ws;                 ws += (size_t)SCAN_N * 4;             // 600 KB
    int*      bsum  = (int*)ws;                 ws += 1024 * 4;
    int*      bcur  = (int*)ws;                 ws += 16 * 4;                         // 8 used
    int*      subcur= (int*)ws;                 ws += (size_t)NPART * NSUB * 4;       // 2 KB
    char*     bkt   = ws;                                                             // bucket region
    unsigned* gpack1 = (unsigned*)bkt;
    unsigned short* gmeta1 = (unsigned short*)(bkt + (size_t)NPART * BCAP * 4);
    unsigned* gpack2 = (unsigned*)(bkt + (size_t)NPART * BCAP * 6);
    unsigned short* gmeta2 = (unsigned short*)(bkt + (size_t)NPART * BCAP * 6
                                                  + (size_t)NPART * NSUB * SUBCAP * 4);
    ushort4*  xw1s  = (ushort4*)bkt;                                     // alias (after C2)
    ushort4*  xw2s  = (ushort4*)(bkt + (size_t)N_NODES * OUT_DIM * 2);   // alias

    // Zero only bcur + subcur (adjacent, 528 ints). cnt is fully written by C1.
    (void)hipMemsetAsync(bcur, 0, (16 + NPART * NSUB) * sizeof(int), stream);

    const int block = 256;

    // A: single read of all 9 streams, LDS-bucket by row partition.
    bucket_kernel<<<NNZ / block, block, 0, stream>>>(
        feat_row, feat_col, feat_vals,
        adj1_row, adj1_col, adj1_vals,
        adj2_row, adj2_col, adj2_vals,
        bcur, gpack1, gmeta1);

    // B: partition bucket -> 64 sub-buckets (XCD-local reads, blockIdx&7 = p).
    subbucket_kernel<<<NPART * BBLK_B, block, 0, stream>>>(
        gpack1, gmeta1, bcur, subcur, gpack2, gmeta2);

    // C1: per-sub-bucket histogram -> cnt (no atomics, covers all slots).
    subhist_kernel<<<NPART * NSUB, 512, 0, stream>>>(gmeta2, subcur, cnt);

    scan_block_kernel<<<SCAN_BLOCKS, 256, 0, stream>>>(cnt, starts, bsum);
    scan_bsum_kernel<<<1, 1024, 0, stream>>>(bsum, SCAN_BLOCKS);
    scan_add_kernel<<<SCAN_BLOCKS, 256, 0, stream>>>(starts, bsum);

    // C2: LDS counting sort per sub-bucket, contiguous coalesced spack writes.
    sort_write_kernel<<<NPART * NSUB, 512, 0, stream>>>(
        gpack2, gmeta2, subcur, starts, spack);

    const int grid_rows = N_NODES / 8;                           // 6250 blocks, 8 rows each
    feat_gather_kernel<<<grid_rows, 256, 0, stream>>>(
        starts, spack, (const float4*)W1, (const float4*)W2, xw1s, xw2s);

    // Dim-sliced adj gather: blockIdx&7 = slice = XCD.
    adj_gather_sliced<<<NSLICE * ADJ_RC, 256, 0, stream>>>(
        starts, spack, xw1s, xw2s, (vf4*)d_out);
}

// Round 9
// 264.929 us; speedup vs baseline: 1.1963x; 1.0317x over previous
//
#include <hip/hip_runtime.h>
#include <hip/hip_fp16.h>

// Problem constants (fixed by the reference setup)
#define N_NODES 50000
#define IN_DIM 256
#define OUT_DIM 128
#define NNZ 800000          // nnz for feat, adj1, adj2 each
#define SCAN_N (3 * N_NODES)        // 150000 row counters (feat | adj1 | adj2)
#define TOTAL_NNZ (3 * NNZ)         // 2.4M sorted entries
#define SCAN_BLOCKS ((SCAN_N + 255) / 256)   // 586
#define NPART 8                      // one row-partition per XCD
#define PART_W (N_NODES / NPART)     // 6250 rows per partition

// Level-1 per-partition bucket capacity.
#define BCAP 310016

// Level-2 sub-buckets: 64 per partition, 98 rows each.
#define NSUB 64
#define SUBW 98
#define SUBCAP 6144
#define ENT_B 4096
#define BBLK_B ((BCAP + ENT_B - 1) / ENT_B)   // 76 blocks per partition

// adj phase: TWO dispatches (rel0 raw-acc, rel1 acc+relu), each gathering from
// ONE xw table -> 32-dim slices (64 B/row-slice) fit per-XCD L2:
//   4 slices x 50000 x 64 B = 3.2 MB per XCD (slice s -> XCDs {s, s+4}).
// 8-lane groups: one FULL 64 B line request per edge-slice.
// Requests: 800K x 4 x 2 = 6.4M full lines vs round-7's 12.8M half-lines.
#define ADJ_SL 4
#define ADJ_RC ((N_NODES + 63) / 64)  // 782 row-chunks of 64 rows

// Native clang vector types — __builtin_nontemporal_* requires these.
typedef float vf4 __attribute__((ext_vector_type(4)));

// Packed entry: [col:16 | fp16(val):16].  adj cols < 50000 < 65536, feat cols < 256.
static __device__ __forceinline__ unsigned pack_cv(int c, float v) {
    return ((unsigned)c << 16) | (unsigned)__half_as_ushort(__float2half(v));
}
static __device__ __forceinline__ int   upk_c(unsigned pk) { return (int)(pk >> 16); }
static __device__ __forceinline__ float upk_v(unsigned pk) {
    return __half2float(__ushort_as_half((unsigned short)(pk & 0xffffu)));
}
static __device__ __forceinline__ float h2f(unsigned short h) {
    return __half2float(__ushort_as_half(h));
}

// -----------------------------------------------------------------------------
// CSR build, three-level counting sort (KNOWN-GOOD round-2 pipeline).
// -----------------------------------------------------------------------------
__global__ void bucket_kernel(const int* __restrict__ fr, const int* __restrict__ fc,
                              const float* __restrict__ fv,
                              const int* __restrict__ a1r, const int* __restrict__ a1c,
                              const float* __restrict__ a1v,
                              const int* __restrict__ a2r, const int* __restrict__ a2c,
                              const float* __restrict__ a2v,
                              int* __restrict__ bcur,
                              unsigned* __restrict__ gpack,
                              unsigned short* __restrict__ gmeta) {
    __shared__ int cnt8[8];
    __shared__ int offc[8];
    __shared__ int gbase[8];
    __shared__ unsigned spk[768];
    __shared__ unsigned short smeta[768];
    int t = threadIdx.x;
    if (t < 8) cnt8[t] = 0;
    __syncthreads();

    int e = blockIdx.x * 256 + t;        // NNZ = 3125 * 256, no tail
    int r[3]; unsigned pk[3]; int loc[3]; int pb[3];
    r[0] = __builtin_nontemporal_load(&fr[e]);
    pk[0] = pack_cv(__builtin_nontemporal_load(&fc[e]),
                    __builtin_nontemporal_load(&fv[e]));
    r[1] = __builtin_nontemporal_load(&a1r[e]);
    pk[1] = pack_cv(__builtin_nontemporal_load(&a1c[e]),
                    __builtin_nontemporal_load(&a1v[e]));
    r[2] = __builtin_nontemporal_load(&a2r[e]);
    pk[2] = pack_cv(__builtin_nontemporal_load(&a2c[e]),
                    __builtin_nontemporal_load(&a2v[e]));
#pragma unroll
    for (int s = 0; s < 3; ++s) {
        pb[s] = r[s] / PART_W;
        loc[s] = atomicAdd(&cnt8[pb[s]], 1);
    }
    __syncthreads();
    if (t < 8) gbase[t] = atomicAdd(&bcur[t], cnt8[t]);
    if (t == 0) {
        int acc = 0;
#pragma unroll
        for (int q = 0; q < 8; ++q) { offc[q] = acc; acc += cnt8[q]; }
    }
    __syncthreads();
#pragma unroll
    for (int s = 0; s < 3; ++s) {
        int pos = offc[pb[s]] + loc[s];
        spk[pos] = pk[s];
        smeta[pos] = (unsigned short)((s << 13) | (r[s] - pb[s] * PART_W));
    }
    __syncthreads();
#pragma unroll
    for (int k = 0; k < 3; ++k) {
        int i = t + k * 256;
        int q = 0;
#pragma unroll
        for (int b = 1; b < 8; ++b) q += (i >= offc[b]);
        int g = q * BCAP + gbase[q] + (i - offc[q]);
        gpack[g] = spk[i];
        gmeta[g] = smeta[i];
    }
}

// Pass B: partition bucket -> 64 sub-buckets (98-row ranges). blockIdx&7 = p.
__global__ void subbucket_kernel(const unsigned* __restrict__ gpack1,
                                 const unsigned short* __restrict__ gmeta1,
                                 const int* __restrict__ bcur,
                                 int* __restrict__ subcur,
                                 unsigned* __restrict__ gpack2,
                                 unsigned short* __restrict__ gmeta2) {
    int p = blockIdx.x & (NPART - 1);
    int chunk = blockIdx.x >> 3;
    int base = chunk * ENT_B;
    int n = bcur[p];
    int cnt = n - base;
    if (cnt <= 0) return;                // uniform across block
    if (cnt > ENT_B) cnt = ENT_B;
    __shared__ int c64[NSUB], off[NSUB], gb[NSUB];
    __shared__ unsigned spk[ENT_B];
    __shared__ unsigned short smt[ENT_B];
    int t = threadIdx.x;
    if (t < NSUB) c64[t] = 0;
    __syncthreads();
    unsigned pk[16]; unsigned short mt[16]; int loc[16]; int sb[16];
#pragma unroll
    for (int k = 0; k < 16; ++k) {
        int i = t + k * 256;
        if (i < cnt) {
            pk[k] = gpack1[p * BCAP + base + i];
            mt[k] = gmeta1[p * BCAP + base + i];
            sb[k] = (int)(mt[k] & 8191u) / SUBW;
            loc[k] = atomicAdd(&c64[sb[k]], 1);
        } else sb[k] = -1;
    }
    __syncthreads();
    if (t == 0) {
        int a = 0;
#pragma unroll
        for (int q = 0; q < NSUB; ++q) { off[q] = a; a += c64[q]; }
    }
    __syncthreads();
    if (t < NSUB && c64[t] > 0) gb[t] = atomicAdd(&subcur[p * NSUB + t], c64[t]);
    __syncthreads();
#pragma unroll
    for (int k = 0; k < 16; ++k) {
        if (sb[k] >= 0) {
            int pos = off[sb[k]] + loc[k];
            spk[pos] = pk[k];
            smt[pos] = mt[k];
        }
    }
    __syncthreads();
    for (int i = t; i < cnt; i += 256) {
        unsigned short m = smt[i];
        int s2 = (int)(m & 8191u) / SUBW;
        int g = (p * NSUB + s2) * SUBCAP + gb[s2] + (i - off[s2]);
        gpack2[g] = spk[i];
        gmeta2[g] = m;
    }
}

// Pass C1: per-sub-bucket histogram -> cnt (plain stores, covers all of cnt).
__global__ __launch_bounds__(512) void subhist_kernel(
        const unsigned short* __restrict__ gmeta2,
        const int* __restrict__ subcur,
        int* __restrict__ cnt) {
    int p = blockIdx.x & (NPART - 1);
    int sub = blockIdx.x >> 3;
    int n = subcur[p * NSUB + sub];
    __shared__ int h[512];
    int t = threadIdx.x;
    h[t] = 0;
    __syncthreads();
    long base = (long)(p * NSUB + sub) * SUBCAP;
    for (int i = t; i < n; i += 512) {
        unsigned short m = gmeta2[base + i];
        int key = (int)(m >> 13) * SUBW + ((int)(m & 8191u) - sub * SUBW);
        atomicAdd(&h[key], 1);
    }
    __syncthreads();
    if (t < 3 * SUBW) {
        int s = t / SUBW, d = t - s * SUBW;
        int rl = sub * SUBW + d;
        if (rl < PART_W) cnt[s * N_NODES + p * PART_W + rl] = h[t];
    }
}

__global__ void scan_block_kernel(const int* __restrict__ cnt,
                                  int* __restrict__ starts,
                                  int* __restrict__ bsum) {
    __shared__ int tmp[256];
    int g = blockIdx.x * 256 + threadIdx.x;
    int v = (g < SCAN_N) ? cnt[g] : 0;
    tmp[threadIdx.x] = v;
    __syncthreads();
    for (int off = 1; off < 256; off <<= 1) {
        int t = (threadIdx.x >= off) ? tmp[threadIdx.x - off] : 0;
        __syncthreads();
        tmp[threadIdx.x] += t;
        __syncthreads();
    }
    int incl = tmp[threadIdx.x];
    if (g < SCAN_N) starts[g] = incl - v;          // exclusive
    if (threadIdx.x == 255) bsum[blockIdx.x] = incl;
}

__global__ void scan_bsum_kernel(int* __restrict__ bsum, int nb) {
    __shared__ int tmp[1024];
    int t = threadIdx.x;
    int v = (t < nb) ? bsum[t] : 0;
    tmp[t] = v;
    __syncthreads();
    for (int off = 1; off < 1024; off <<= 1) {
        int x = (t >= off) ? tmp[t - off] : 0;
        __syncthreads();
        tmp[t] += x;
        __syncthreads();
    }
    if (t < nb) bsum[t] = tmp[t] - v;              // exclusive block offsets
}

__global__ void scan_add_kernel(int* __restrict__ starts,
                                const int* __restrict__ bsum) {
    int g = blockIdx.x * 256 + threadIdx.x;
    if (g < SCAN_N) starts[g] += bsum[blockIdx.x];
}

// Pass C2: LDS counting sort of one sub-bucket -> three contiguous spack ranges.
__global__ __launch_bounds__(512) void sort_write_kernel(
        const unsigned* __restrict__ gpack2,
        const unsigned short* __restrict__ gmeta2,
        const int* __restrict__ subcur,
        const int* __restrict__ starts,
        unsigned* __restrict__ spack) {
    int p = blockIdx.x & (NPART - 1);
    int sub = blockIdx.x >> 3;
    int n = subcur[p * NSUB + sub];
    __shared__ int h[512];
    __shared__ int e[512];
    __shared__ int cur[512];
    __shared__ unsigned sorted[SUBCAP];
    int t = threadIdx.x;
    h[t] = 0;
    __syncthreads();
    long base = (long)(p * NSUB + sub) * SUBCAP;
    unsigned pk[12]; short ky[12];
#pragma unroll
    for (int k = 0; k < 12; ++k) {           // SUBCAP = 12*512 exactly
        int i = t + k * 512;
        if (i < n) {
            pk[k] = gpack2[base + i];
            unsigned short m = gmeta2[base + i];
            int key = (int)(m >> 13) * SUBW + ((int)(m & 8191u) - sub * SUBW);
            ky[k] = (short)key;
            atomicAdd(&h[key], 1);
        } else ky[k] = -1;
    }
    __syncthreads();
    e[t] = h[t];
    __syncthreads();
    for (int off = 1; off < 512; off <<= 1) {
        int v = (t >= off) ? e[t - off] : 0;
        __syncthreads();
        e[t] += v;
        __syncthreads();
    }
    int excl = e[t] - h[t];
    __syncthreads();
    e[t] = excl;
    cur[t] = excl;
    __syncthreads();
#pragma unroll
    for (int k = 0; k < 12; ++k) {
        if (ky[k] >= 0) {
            int pos = atomicAdd(&cur[ky[k]], 1);
            sorted[pos] = pk[k];
        }
    }
    __syncthreads();
    int s1 = e[SUBW];
    int s2 = e[2 * SUBW];
    int rb = p * PART_W + sub * SUBW;
    int gb0 = starts[rb];
    int gb1 = starts[N_NODES + rb];
    int gb2 = starts[2 * N_NODES + rb];
#pragma unroll
    for (int k = 0; k < 12; ++k) {
        int i = t + k * 512;
        if (i < n) {
            unsigned v = sorted[i];
            int dst;
            if (i < s1)      dst = gb0 + i;
            else if (i < s2) dst = gb1 + (i - s1);
            else             dst = gb2 + (i - s2);
            spack[dst] = v;
        }
    }
}

// -----------------------------------------------------------------------------
// Phase 1: per-row gather  xw{1,2}[r,:] = sum_e v_e * W{1,2}[c_e,:]
// Output in 32-dim-slice layout: xw[s][r][d32], s in [0,4), 64 B per row-slice.
// Lane l holds dims [4l,4l+4) = slice l>>3, ushort4 offset l&7.
// -----------------------------------------------------------------------------
__global__ void feat_gather_kernel(const int* __restrict__ starts,
                                   const unsigned* __restrict__ spack,
                                   const float4* __restrict__ W1,
                                   const float4* __restrict__ W2,
                                   ushort4* __restrict__ xw1s,
                                   ushort4* __restrict__ xw2s) {
    int lane = threadIdx.x & 31;
    int sub  = threadIdx.x >> 5;
    int r = blockIdx.x * 8 + sub;
    if (r >= N_NODES) return;
    int s = starts[r];
    int e = starts[r + 1];            // starts[50000] == 800000 (adj1 base)
    float4 a1 = make_float4(0.f, 0.f, 0.f, 0.f);
    float4 a2 = make_float4(0.f, 0.f, 0.f, 0.f);
    for (int base = s; base < e; base += 32) {
        int n = e - base;
        int m = (n < 32) ? n : 32;
        unsigned pk = (lane < m) ? spack[base + lane] : 0u;
        int j = 0;
        for (; j + 7 < m; j += 8) {
            unsigned pp[8]; float4 w1v[8]; float4 w2v[8];
#pragma unroll
            for (int k = 0; k < 8; ++k) pp[k] = __shfl(pk, j + k, 32);
#pragma unroll
            for (int k = 0; k < 8; ++k) {
                int c = upk_c(pp[k]);
                w1v[k] = W1[c * 32 + lane];
                w2v[k] = W2[c * 32 + lane];
            }
#pragma unroll
            for (int k = 0; k < 8; ++k) {
                float v = upk_v(pp[k]);
                a1.x += v * w1v[k].x; a1.y += v * w1v[k].y;
                a1.z += v * w1v[k].z; a1.w += v * w1v[k].w;
                a2.x += v * w2v[k].x; a2.y += v * w2v[k].y;
                a2.z += v * w2v[k].z; a2.w += v * w2v[k].w;
            }
        }
        for (; j + 3 < m; j += 4) {
            unsigned pp[4]; float4 w1v[4]; float4 w2v[4];
#pragma unroll
            for (int k = 0; k < 4; ++k) pp[k] = __shfl(pk, j + k, 32);
#pragma unroll
            for (int k = 0; k < 4; ++k) {
                int c = upk_c(pp[k]);
                w1v[k] = W1[c * 32 + lane];
                w2v[k] = W2[c * 32 + lane];
            }
#pragma unroll
            for (int k = 0; k < 4; ++k) {
                float v = upk_v(pp[k]);
                a1.x += v * w1v[k].x; a1.y += v * w1v[k].y;
                a1.z += v * w1v[k].z; a1.w += v * w1v[k].w;
                a2.x += v * w2v[k].x; a2.y += v * w2v[k].y;
                a2.z += v * w2v[k].z; a2.w += v * w2v[k].w;
            }
        }
        for (; j < m; ++j) {
            unsigned pj = __shfl(pk, j, 32);
            int c = upk_c(pj);
            float v = upk_v(pj);
            float4 w1 = W1[c * 32 + lane];
            float4 w2 = W2[c * 32 + lane];
            a1.x += v * w1.x; a1.y += v * w1.y; a1.z += v * w1.z; a1.w += v * w1.w;
            a2.x += v * w2.x; a2.y += v * w2.y; a2.z += v * w2.z; a2.w += v * w2.w;
        }
    }
    ushort4 q1, q2;
    q1.x = __half_as_ushort(__float2half(a1.x)); q1.y = __half_as_ushort(__float2half(a1.y));
    q1.z = __half_as_ushort(__float2half(a1.z)); q1.w = __half_as_ushort(__float2half(a1.w));
    q2.x = __half_as_ushort(__float2half(a2.x)); q2.y = __half_as_ushort(__float2half(a2.y));
    q2.z = __half_as_ushort(__float2half(a2.z)); q2.w = __half_as_ushort(__float2half(a2.w));
    // 32-dim-slice store: lanes {8k..8k+7} write one full 64 B line.
    size_t idx = (size_t)(lane >> 3) * (N_NODES * 8) + (size_t)r * 8 + (lane & 7);
    xw1s[idx] = q1;
    xw2s[idx] = q2;
}

// -----------------------------------------------------------------------------
// Phase 2, split by relation into two plain (non-template) dispatches:
//   adj_pass_rel0: out[r, 32s:32s+32]  = sum_adj1 v * xw1[s][c][:]   (raw, nt)
//   adj_pass_rel1: out = relu(out_prev + sum_adj2 v * xw2[s][c][:])
// 32-dim slices: per-XCD working set = ONE table slice = 3.2 MB -> L2-resident.
// 8-lane groups: each edge-slice is ONE full-64B-line request; 6.4M requests
// total vs round-7's 12.8M half-line requests (theory: L2 request-rate bound).
// prev/out use nt (keep L2 for the table); spack loads plain (round-6 lesson).
// -----------------------------------------------------------------------------
__global__ __launch_bounds__(512) void adj_pass_rel0(
        const int* __restrict__ starts,
        const unsigned* __restrict__ spack,
        const ushort4* __restrict__ xws,
        vf4* __restrict__ out) {
    int s  = blockIdx.x & (ADJ_SL - 1);
    int rc = blockIdx.x >> 2;
    int g  = threadIdx.x >> 3;          // 64 row-groups per block
    int q  = threadIdx.x & 7;
    int r  = rc * 64 + g;
    bool valid = (r < N_NODES);
    vf4 acc = {0.f, 0.f, 0.f, 0.f};
    const ushort4* __restrict__ sl = xws + (size_t)s * (N_NODES * 8);
    size_t oidx = (size_t)r * 32 + s * 8 + q;

    int st = 0, en = 0;
    if (valid) {
        st = starts[N_NODES + r];
        en = starts[N_NODES + r + 1];   // r+1 <= 50000 -> adj2 base, safe
    }
    for (int base = st; base < en; base += 16) {
        int m = en - base;
        // zero-padded: pack 0 -> c=0 (safe addr), v=0 (exact)
        unsigned pk0 = (q < m)     ? spack[base + q]     : 0u;
        unsigned pk1 = (8 + q < m) ? spack[base + 8 + q] : 0u;
        {
            unsigned pp[8]; ushort4 xx[8];
#pragma unroll
            for (int k = 0; k < 8; ++k) pp[k] = __shfl(pk0, k, 8);
#pragma unroll
            for (int k = 0; k < 8; ++k) xx[k] = sl[upk_c(pp[k]) * 8 + q];
#pragma unroll
            for (int k = 0; k < 8; ++k) {
                float v = upk_v(pp[k]);
                acc.x += v * h2f(xx[k].x); acc.y += v * h2f(xx[k].y);
                acc.z += v * h2f(xx[k].z); acc.w += v * h2f(xx[k].w);
            }
        }
        if (m <= 8) continue;
        {
            unsigned pp[8]; ushort4 xx[8];
#pragma unroll
            for (int k = 0; k < 8; ++k) pp[k] = __shfl(pk1, k, 8);
#pragma unroll
            for (int k = 0; k < 8; ++k) xx[k] = sl[upk_c(pp[k]) * 8 + q];
#pragma unroll
            for (int k = 0; k < 8; ++k) {
                float v = upk_v(pp[k]);
                acc.x += v * h2f(xx[k].x); acc.y += v * h2f(xx[k].y);
                acc.z += v * h2f(xx[k].z); acc.w += v * h2f(xx[k].w);
            }
        }
    }
    if (valid) __builtin_nontemporal_store(acc, &out[oidx]);   // raw partial sum
}

__global__ __launch_bounds__(512) void adj_pass_rel1(
        const int* __restrict__ starts,
        const unsigned* __restrict__ spack,
        const ushort4* __restrict__ xws,
        vf4* __restrict__ out) {
    int s  = blockIdx.x & (ADJ_SL - 1);
    int rc = blockIdx.x >> 2;
    int g  = threadIdx.x >> 3;
    int q  = threadIdx.x & 7;
    int r  = rc * 64 + g;
    bool valid = (r < N_NODES);
    vf4 acc = {0.f, 0.f, 0.f, 0.f};
    const ushort4* __restrict__ sl = xws + (size_t)s * (N_NODES * 8);
    size_t oidx = (size_t)r * 32 + s * 8 + q;

    int st = 0, en = 0;
    if (valid) {
        st = starts[2 * N_NODES + r];
        en = (r == N_NODES - 1) ? TOTAL_NNZ : starts[2 * N_NODES + r + 1];
    }
    vf4 prev = {0.f, 0.f, 0.f, 0.f};
    if (valid) prev = __builtin_nontemporal_load(&out[oidx]);  // early, overlaps loop

    for (int base = st; base < en; base += 16) {
        int m = en - base;
        unsigned pk0 = (q < m)     ? spack[base + q]     : 0u;
        unsigned pk1 = (8 + q < m) ? spack[base + 8 + q] : 0u;
        {
            unsigned pp[8]; ushort4 xx[8];
#pragma unroll
            for (int k = 0; k < 8; ++k) pp[k] = __shfl(pk0, k, 8);
#pragma unroll
            for (int k = 0; k < 8; ++k) xx[k] = sl[upk_c(pp[k]) * 8 + q];
#pragma unroll
            for (int k = 0; k < 8; ++k) {
                float v = upk_v(pp[k]);
                acc.x += v * h2f(xx[k].x); acc.y += v * h2f(xx[k].y);
                acc.z += v * h2f(xx[k].z); acc.w += v * h2f(xx[k].w);
            }
        }
        if (m <= 8) continue;
        {
            unsigned pp[8]; ushort4 xx[8];
#pragma unroll
            for (int k = 0; k < 8; ++k) pp[k] = __shfl(pk1, k, 8);
#pragma unroll
            for (int k = 0; k < 8; ++k) xx[k] = sl[upk_c(pp[k]) * 8 + q];
#pragma unroll
            for (int k = 0; k < 8; ++k) {
                float v = upk_v(pp[k]);
                acc.x += v * h2f(xx[k].x); acc.y += v * h2f(xx[k].y);
                acc.z += v * h2f(xx[k].z); acc.w += v * h2f(xx[k].w);
            }
        }
    }
    if (valid) {
        vf4 res;
        res.x = fmaxf(acc.x + prev.x, 0.f);
        res.y = fmaxf(acc.y + prev.y, 0.f);
        res.z = fmaxf(acc.z + prev.z, 0.f);
        res.w = fmaxf(acc.w + prev.w, 0.f);
        __builtin_nontemporal_store(res, &out[oidx]);
    }
}

extern "C" void kernel_launch(void* const* d_in, const int* in_sizes, int n_in,
                              void* d_out, int out_size, void* d_ws, size_t ws_size,
                              hipStream_t stream) {
    const int*   feat_row  = (const int*)  d_in[0];
    const int*   feat_col  = (const int*)  d_in[1];
    const float* feat_vals = (const float*)d_in[2];
    const int*   adj1_row  = (const int*)  d_in[3];
    const int*   adj1_col  = (const int*)  d_in[4];
    const float* adj1_vals = (const float*)d_in[5];
    const int*   adj2_row  = (const int*)  d_in[6];
    const int*   adj2_col  = (const int*)  d_in[7];
    const float* adj2_vals = (const float*)d_in[8];
    const float* W1        = (const float*)d_in[9];
    const float* W2        = (const float*)d_in[10];

    // Workspace layout. Bucket storage (~33.8 MB) is dead after sort_write,
    // so xw1s/xw2s (25.6 MB) alias it. Total footprint ~44.6 MB.
    char* ws = (char*)d_ws;
    unsigned* spack = (unsigned*)ws;            ws += (size_t)TOTAL_NNZ * 4;          // 9.6 MB
    int*      cnt   = (int*)ws;                 ws += (size_t)SCAN_N * 4;             // 600 KB
    int*      starts= (int*)ws;                 ws += (size_t)SCAN_N * 4;             // 600 KB
    int*      bsum  = (int*)ws;                 ws += 1024 * 4;
    int*      bcur  = (int*)ws;                 ws += 16 * 4;                         // 8 used
    int*      subcur= (int*)ws;                 ws += (size_t)NPART * NSUB * 4;       // 2 KB
    char*     bkt   = ws;                                                             // bucket region
    unsigned* gpack1 = (unsigned*)bkt;
    unsigned short* gmeta1 = (unsigned short*)(bkt + (size_t)NPART * BCAP * 4);
    unsigned* gpack2 = (unsigned*)(bkt + (size_t)NPART * BCAP * 6);
    unsigned short* gmeta2 = (unsigned short*)(bkt + (size_t)NPART * BCAP * 6
                                                  + (size_t)NPART * NSUB * SUBCAP * 4);
    ushort4*  xw1s  = (ushort4*)bkt;                                     // alias (after C2)
    ushort4*  xw2s  = (ushort4*)(bkt + (size_t)N_NODES * OUT_DIM * 2);   // alias

    // Zero only bcur + subcur (adjacent, 528 ints). cnt is fully written by C1.
    (void)hipMemsetAsync(bcur, 0, (16 + NPART * NSUB) * sizeof(int), stream);

    const int block = 256;

    // A: single read of all 9 streams, LDS-bucket by row partition.
    bucket_kernel<<<NNZ / block, block, 0, stream>>>(
        feat_row, feat_col, feat_vals,
        adj1_row, adj1_col, adj1_vals,
        adj2_row, adj2_col, adj2_vals,
        bcur, gpack1, gmeta1);

    // B: partition bucket -> 64 sub-buckets (XCD-local reads, blockIdx&7 = p).
    subbucket_kernel<<<NPART * BBLK_B, block, 0, stream>>>(
        gpack1, gmeta1, bcur, subcur, gpack2, gmeta2);

    // C1: per-sub-bucket histogram -> cnt (no atomics, covers all slots).
    subhist_kernel<<<NPART * NSUB, 512, 0, stream>>>(gmeta2, subcur, cnt);

    scan_block_kernel<<<SCAN_BLOCKS, 256, 0, stream>>>(cnt, starts, bsum);
    scan_bsum_kernel<<<1, 1024, 0, stream>>>(bsum, SCAN_BLOCKS);
    scan_add_kernel<<<SCAN_BLOCKS, 256, 0, stream>>>(starts, bsum);

    // C2: LDS counting sort per sub-bucket, contiguous coalesced spack writes.
    sort_write_kernel<<<NPART * NSUB, 512, 0, stream>>>(
        gpack2, gmeta2, subcur, starts, spack);

    const int grid_rows = N_NODES / 8;                           // 6250 blocks, 8 rows each
    feat_gather_kernel<<<grid_rows, 256, 0, stream>>>(
        starts, spack, (const float4*)W1, (const float4*)W2, xw1s, xw2s);

    // Phase 2: rel-split, 32-dim slices, full-line gathers.
    adj_pass_rel0<<<ADJ_SL * ADJ_RC, 512, 0, stream>>>(
        starts, spack, xw1s, (vf4*)d_out);
    adj_pass_rel1<<<ADJ_SL * ADJ_RC, 512, 0, stream>>>(
        starts, spack, xw2s, (vf4*)d_out);
}